// Round 2
// baseline (301.136 us; speedup 1.0000x reference)
//
#include <hip/hip_runtime.h>
#include <hip/hip_bf16.h>

// Causal flash attention fwd, B=2 H=16 S=2048 D=64, fp32 I/O, bf16 MFMA compute.
// One workgroup (4 waves, 256 thr) handles one 64-row Q block of one (b,h).
// Grid = 32 bh * 32 qblocks = 1024. KV staged in 64-wide tiles:
//   K:  LDS row-major [kv][d] bf16, XOR-swizzled (byte ^= (row&7)<<4)
//   V:  LDS transposed [d][kv] bf16, stride 68 elements (136B, 8B-aligned reads)
//   P:  per-wave LDS [16][72] bf16 re-fragmentation buffer for the PV A-operand
// MFMA 16x16x32_bf16: A row = lane&15, k = 8*(lane>>4)+e ; C/D col = lane&15,
// row = 4*(lane>>4)+i (guide §3, m89-verified).

typedef unsigned int u32;
typedef unsigned short u16;
typedef unsigned long long u64;
typedef __attribute__((ext_vector_type(8))) short short8;
typedef __attribute__((ext_vector_type(4))) float f32x4;

#define DEV static __device__ __forceinline__

constexpr int S_ = 2048, D_ = 64;
constexpr float SCL = 0.125f * 1.44269504089f; // D^-0.5 * log2(e)

DEV u16 f2bf(float f) {
  u32 u = __builtin_bit_cast(u32, f);
  u += 0x7fffu + ((u >> 16) & 1u);   // RNE; inputs are finite
  return (u16)(u >> 16);
}

struct Q4 { u32 w[4]; };
struct P2 { u64 a, b; };

__global__ __launch_bounds__(256, 2)
void fattn(const float* __restrict__ Qg, const float* __restrict__ Kg,
           const float* __restrict__ Vg, float* __restrict__ Og)
{
  __shared__ __align__(16) u16 Kl[64 * 64];        // 8 KiB, swizzled
  __shared__ __align__(16) u16 Vt[64 * 68];        // 8.5 KiB, [d][kv] pad-68
  __shared__ __align__(16) u16 Pl[4][16 * 72];     // 9 KiB, per-wave

  const int tid  = threadIdx.x;
  const int wid  = tid >> 6;
  const int lane = tid & 63;
  const int c    = lane & 15;
  const int g    = lane >> 4;

  const int bh = blockIdx.x >> 5;       // 0..31
  const int qb = blockIdx.x & 31;       // 0..31
  const int q0 = qb * 64;
  const int ntiles = qb + 1;

  const float* Qb = Qg + (size_t)bh * S_ * D_;
  const float* Kb = Kg + (size_t)bh * S_ * D_;
  const float* Vb = Vg + (size_t)bh * S_ * D_;
  float*       Ob = Og + (size_t)bh * S_ * D_;

  char* Kbyte = (char*)Kl;
  char* Vbyte = (char*)Vt;
  char* Pbyte = (char*)(Pl[wid]);

  // ---- Q fragments (A operand), scale folded into bf16 conversion ----
  const int qrow = q0 + wid * 16 + c;
  short8 qf[2];
  for (int kc = 0; kc < 2; ++kc) {
    const float* qp = Qb + (size_t)qrow * D_ + kc * 32 + 8 * g;
    float4 x = *(const float4*)qp;
    float4 y = *(const float4*)(qp + 4);
    Q4 q;
    q.w[0] = (u32)f2bf(x.x * SCL) | ((u32)f2bf(x.y * SCL) << 16);
    q.w[1] = (u32)f2bf(x.z * SCL) | ((u32)f2bf(x.w * SCL) << 16);
    q.w[2] = (u32)f2bf(y.x * SCL) | ((u32)f2bf(y.y * SCL) << 16);
    q.w[3] = (u32)f2bf(y.z * SCL) | ((u32)f2bf(y.w * SCL) << 16);
    qf[kc] = __builtin_bit_cast(short8, q);
  }

  f32x4 oa[4];
  for (int nd = 0; nd < 4; ++nd) oa[nd] = f32x4{0.f, 0.f, 0.f, 0.f};
  float mrow[4], lrow[4];
  for (int i = 0; i < 4; ++i) { mrow[i] = -__builtin_inff(); lrow[i] = 0.f; }

  for (int t = 0; t < ntiles; ++t) {
    const int kv0 = t * 64;
    __syncthreads();   // all waves done reading previous K/Vt tile

    // ---- stage K tile (XOR-swizzled rows) ----
    {
      const int cf4 = tid & 15;
      for (int p = 0; p < 4; ++p) {
        const int row = (tid >> 4) + p * 16;
        float4 v = *(const float4*)(Kb + (size_t)(kv0 + row) * D_ + cf4 * 4);
        u64 w = (u64)((u32)f2bf(v.x) | ((u32)f2bf(v.y) << 16)) |
                ((u64)((u32)f2bf(v.z) | ((u32)f2bf(v.w) << 16)) << 32);
        *(u64*)(Kbyte + row * 128 + ((cf4 * 8) ^ ((row & 7) << 4))) = w;
      }
      // ---- stage V transposed: Vt[d][kv], kv-pairs packed as u32 ----
      for (int p = 0; p < 2; ++p) {
        const int kvl = 2 * (tid >> 4) + p * 32;
        const int d0  = cf4 * 4;
        const float* s0 = Vb + (size_t)(kv0 + kvl) * D_ + d0;
        float4 a = *(const float4*)s0;
        float4 b = *(const float4*)(s0 + D_);
        *(u32*)(Vbyte + (d0 + 0) * 136 + kvl * 2) = (u32)f2bf(a.x) | ((u32)f2bf(b.x) << 16);
        *(u32*)(Vbyte + (d0 + 1) * 136 + kvl * 2) = (u32)f2bf(a.y) | ((u32)f2bf(b.y) << 16);
        *(u32*)(Vbyte + (d0 + 2) * 136 + kvl * 2) = (u32)f2bf(a.z) | ((u32)f2bf(b.z) << 16);
        *(u32*)(Vbyte + (d0 + 3) * 136 + kvl * 2) = (u32)f2bf(a.w) | ((u32)f2bf(b.w) << 16);
      }
    }
    __syncthreads();

    // ---- QK^T: S[q0+wid*16+*, kv0+*] ----
    f32x4 sa[4];
    for (int n = 0; n < 4; ++n) {
      sa[n] = f32x4{0.f, 0.f, 0.f, 0.f};
      const int rowk = n * 16 + c;
      const int base = rowk * 128;
      const int swz  = (rowk & 7) << 4;
      for (int kc = 0; kc < 2; ++kc) {
        short8 kf = *(const short8*)(Kbyte + base + ((kc * 64 + 16 * g) ^ swz));
        sa[n] = __builtin_amdgcn_mfma_f32_16x16x32_bf16(qf[kc], kf, sa[n], 0, 0, 0);
      }
    }

    // ---- causal mask + online softmax (scores already in log2 domain) ----
    const bool diag = (t == ntiles - 1);
    float pp[4][4];
    for (int i = 0; i < 4; ++i) {
      const int qg_ = q0 + wid * 16 + 4 * g + i;
      float s0v = sa[0][i], s1v = sa[1][i], s2v = sa[2][i], s3v = sa[3][i];
      if (diag) {
        if (kv0 +  0 + c > qg_) s0v = -__builtin_inff();
        if (kv0 + 16 + c > qg_) s1v = -__builtin_inff();
        if (kv0 + 32 + c > qg_) s2v = -__builtin_inff();
        if (kv0 + 48 + c > qg_) s3v = -__builtin_inff();
      }
      float mx = fmaxf(fmaxf(s0v, s1v), fmaxf(s2v, s3v));
      mx = fmaxf(mx, __shfl_xor(mx, 1));
      mx = fmaxf(mx, __shfl_xor(mx, 2));
      mx = fmaxf(mx, __shfl_xor(mx, 4));
      mx = fmaxf(mx, __shfl_xor(mx, 8));
      const float nm = fmaxf(mrow[i], mx);
      const float al = exp2f(mrow[i] - nm);
      mrow[i] = nm;
      float p0 = exp2f(s0v - nm), p1 = exp2f(s1v - nm);
      float p2 = exp2f(s2v - nm), p3 = exp2f(s3v - nm);
      pp[0][i] = p0; pp[1][i] = p1; pp[2][i] = p2; pp[3][i] = p3;
      float ls = p0 + p1 + p2 + p3;
      ls += __shfl_xor(ls, 1);
      ls += __shfl_xor(ls, 2);
      ls += __shfl_xor(ls, 4);
      ls += __shfl_xor(ls, 8);
      lrow[i] = lrow[i] * al + ls;
      oa[0][i] *= al; oa[1][i] *= al; oa[2][i] *= al; oa[3][i] *= al;
    }

    // ---- P -> per-wave LDS (bf16), rows padded to 72 ----
    for (int n = 0; n < 4; ++n)
      for (int i = 0; i < 4; ++i)
        *(u16*)(Pbyte + ((4 * g + i) * 72 + n * 16 + c) * 2) = f2bf(pp[n][i]);

    // ---- PV: O += P @ V ----
    for (int kc = 0; kc < 2; ++kc) {
      short8 af = *(const short8*)(Pbyte + c * 144 + kc * 64 + 16 * g);
      for (int nd = 0; nd < 4; ++nd) {
        const int d = nd * 16 + c;
        P2 pv;
        pv.a = *(const u64*)(Vbyte + d * 136 + kc * 64 + 16 * g);
        pv.b = *(const u64*)(Vbyte + d * 136 + kc * 64 + 16 * g + 8);
        short8 vf = __builtin_bit_cast(short8, pv);
        oa[nd] = __builtin_amdgcn_mfma_f32_16x16x32_bf16(af, vf, oa[nd], 0, 0, 0);
      }
    }
  }

  // ---- epilogue: normalize and store ----
  for (int i = 0; i < 4; ++i) {
    const float rl = 1.f / lrow[i];
    float* op = Ob + (size_t)(q0 + wid * 16 + 4 * g + i) * D_ + c;
    op[0]  = oa[0][i] * rl;
    op[16] = oa[1][i] * rl;
    op[32] = oa[2][i] * rl;
    op[48] = oa[3][i] * rl;
  }
}

extern "C" void kernel_launch(void* const* d_in, const int* in_sizes, int n_in,
                              void* d_out, int out_size, void* d_ws, size_t ws_size,
                              hipStream_t stream) {
  const float* q = (const float*)d_in[0];
  const float* k = (const float*)d_in[1];
  const float* v = (const float*)d_in[2];
  float* o = (float*)d_out;
  dim3 grid(1024), block(256);
  fattn<<<grid, block, 0, stream>>>(q, k, v, o);
}

// Round 3
// 201.945 us; speedup vs baseline: 1.4912x; 1.4912x over previous
//
#include <hip/hip_runtime.h>
#include <hip/hip_bf16.h>

// Causal flash attention fwd, B=2 H=16 S=2048 D=64, fp32 I/O, bf16 MFMA compute.
// R2 changes vs R1 baseline (244us, Mfma 2.9%, Occ 13.5%):
//  (a) balanced block swizzle: stride-256-resident blocks get qb {b,31-b,(b+16)&31,(15-b)&31}
//      (sum 62) so every CU's 4 resident blocks carry equal total tile work.
//  (b) T14 async-STAGE: tile t+1 global loads issued into regs before tile t compute;
//      barrier B is raw s_barrier + lgkmcnt(0) only (no vmcnt drain) so loads stay in flight.
// K: LDS [kv][d] bf16 XOR-swizzled (byte ^= (row&7)<<4); V: LDS [d][kv] bf16 stride 68;
// P: per-wave [16][72] bf16. MFMA 16x16x32_bf16 layouts per guide §3 (m89-verified).

typedef unsigned int u32;
typedef unsigned short u16;
typedef unsigned long long u64;
typedef __attribute__((ext_vector_type(8))) short short8;
typedef __attribute__((ext_vector_type(4))) float f32x4;

#define DEV static __device__ __forceinline__

constexpr int S_ = 2048, D_ = 64;
constexpr float SCL = 0.125f * 1.44269504089f; // D^-0.5 * log2(e)

DEV u16 f2bf(float f) {
  u32 u = __builtin_bit_cast(u32, f);
  u += 0x7fffu + ((u >> 16) & 1u);   // RNE; inputs are finite
  return (u16)(u >> 16);
}
DEV u32 pk2(float lo, float hi) { return (u32)f2bf(lo) | ((u32)f2bf(hi) << 16); }
DEV u64 pk4(float4 v) {
  return (u64)pk2(v.x, v.y) | ((u64)pk2(v.z, v.w) << 32);
}

struct Q4 { u32 w[4]; };
struct P2 { u64 a, b; };

__global__ __launch_bounds__(256, 4)
void fattn(const float* __restrict__ Qg, const float* __restrict__ Kg,
           const float* __restrict__ Vg, float* __restrict__ Og)
{
  __shared__ __align__(16) u16 Kl[64 * 64];        // 8 KiB, swizzled
  __shared__ __align__(16) u16 Vt[64 * 68];        // 8.5 KiB, [d][kv] pad-68
  __shared__ __align__(16) u16 Pl[4][16 * 72];     // 9 KiB, per-wave

  const int tid  = threadIdx.x;
  const int wid  = tid >> 6;
  const int lane = tid & 63;
  const int c    = lane & 15;
  const int g    = lane >> 4;

  // ---- balanced block swizzle: CU-resident set {j, j+256, j+512, j+768} gets
  // qb values {b, 31-b, (b+16)&31, (15-b)&31} -> equal work per CU ----
  const int n  = blockIdx.x;
  const int j  = n & 255, kq = n >> 8;
  const int b5 = j & 31,  r3 = j >> 5;
  const int bh = kq * 8 + r3;
  int qb;
  switch (kq) {
    case 0:  qb = b5;              break;
    case 1:  qb = 31 - b5;         break;
    case 2:  qb = (b5 + 16) & 31;  break;
    default: qb = (15 - b5) & 31;  break;
  }
  const int q0 = qb * 64;
  const int ntiles = qb + 1;

  const float* Qb = Qg + (size_t)bh * S_ * D_;
  const float* Kb = Kg + (size_t)bh * S_ * D_;
  const float* Vb = Vg + (size_t)bh * S_ * D_;
  float*       Ob = Og + (size_t)bh * S_ * D_;

  char* Kbyte = (char*)Kl;
  char* Vbyte = (char*)Vt;
  char* Pbyte = (char*)(Pl[wid]);

  // ---- Q fragments (A operand), scale folded into bf16 conversion ----
  const int qrow = q0 + wid * 16 + c;
  short8 qf[2];
  for (int kc = 0; kc < 2; ++kc) {
    const float* qp = Qb + (size_t)qrow * D_ + kc * 32 + 8 * g;
    float4 x = *(const float4*)qp;
    float4 y = *(const float4*)(qp + 4);
    Q4 q;
    q.w[0] = pk2(x.x * SCL, x.y * SCL);
    q.w[1] = pk2(x.z * SCL, x.w * SCL);
    q.w[2] = pk2(y.x * SCL, y.y * SCL);
    q.w[3] = pk2(y.z * SCL, y.w * SCL);
    qf[kc] = __builtin_bit_cast(short8, q);
  }

  f32x4 oa[4];
  for (int nd = 0; nd < 4; ++nd) oa[nd] = f32x4{0.f, 0.f, 0.f, 0.f};
  float mrow[4], lrow[4];
  for (int i = 0; i < 4; ++i) { mrow[i] = -__builtin_inff(); lrow[i] = 0.f; }

  // ---- prefetch registers (tile t+1 in flight during tile t compute) ----
  const int cf4  = tid & 15;
  const int krow = tid >> 4;      // 0..15
  const int d0   = cf4 * 4;
  float4 pk0, pk1, pk2v, pk3, pa0, pb0, pa1, pb1;

#define ISSUE(T) do {                                                     \
    const float* Kt_ = Kb + (size_t)(T) * 64 * D_;                        \
    const float* Vg_ = Vb + (size_t)(T) * 64 * D_;                        \
    pk0 = *(const float4*)(Kt_ + (size_t)(krow     ) * D_ + d0);          \
    pk1 = *(const float4*)(Kt_ + (size_t)(krow + 16) * D_ + d0);          \
    pk2v = *(const float4*)(Kt_ + (size_t)(krow + 32) * D_ + d0);         \
    pk3 = *(const float4*)(Kt_ + (size_t)(krow + 48) * D_ + d0);          \
    const float* s0_ = Vg_ + (size_t)(2 * krow     ) * D_ + d0;           \
    const float* s1_ = Vg_ + (size_t)(2 * krow + 32) * D_ + d0;           \
    pa0 = *(const float4*)s0_;  pb0 = *(const float4*)(s0_ + D_);         \
    pa1 = *(const float4*)s1_;  pb1 = *(const float4*)(s1_ + D_);         \
  } while (0)

  ISSUE(0);

  for (int t = 0; t < ntiles; ++t) {
    const int kv0 = t * 64;
    __syncthreads();   // barrier A: all waves done reading previous K/Vt tile

    // ---- write prefetched tile -> LDS (K swizzled; V transposed) ----
    {
      const int r0 = krow, r1 = krow + 16, r2 = krow + 32, r3r = krow + 48;
      *(u64*)(Kbyte + r0  * 128 + ((cf4 * 8) ^ ((r0  & 7) << 4))) = pk4(pk0);
      *(u64*)(Kbyte + r1  * 128 + ((cf4 * 8) ^ ((r1  & 7) << 4))) = pk4(pk1);
      *(u64*)(Kbyte + r2  * 128 + ((cf4 * 8) ^ ((r2  & 7) << 4))) = pk4(pk2v);
      *(u64*)(Kbyte + r3r * 128 + ((cf4 * 8) ^ ((r3r & 7) << 4))) = pk4(pk3);
      const int kvl0 = 2 * krow, kvl1 = 2 * krow + 32;
      *(u32*)(Vbyte + (d0 + 0) * 136 + kvl0 * 2) = pk2(pa0.x, pb0.x);
      *(u32*)(Vbyte + (d0 + 1) * 136 + kvl0 * 2) = pk2(pa0.y, pb0.y);
      *(u32*)(Vbyte + (d0 + 2) * 136 + kvl0 * 2) = pk2(pa0.z, pb0.z);
      *(u32*)(Vbyte + (d0 + 3) * 136 + kvl0 * 2) = pk2(pa0.w, pb0.w);
      *(u32*)(Vbyte + (d0 + 0) * 136 + kvl1 * 2) = pk2(pa1.x, pb1.x);
      *(u32*)(Vbyte + (d0 + 1) * 136 + kvl1 * 2) = pk2(pa1.y, pb1.y);
      *(u32*)(Vbyte + (d0 + 2) * 136 + kvl1 * 2) = pk2(pa1.z, pb1.z);
      *(u32*)(Vbyte + (d0 + 3) * 136 + kvl1 * 2) = pk2(pa1.w, pb1.w);
    }

    // ---- issue next tile's global loads (stay in flight across barrier B) ----
    if (t + 1 < ntiles) ISSUE(t + 1);

    // barrier B: drain LDS writes only — NOT vmcnt (keep prefetch in flight)
    asm volatile("s_waitcnt lgkmcnt(0)" ::: "memory");
    __builtin_amdgcn_s_barrier();
    asm volatile("" ::: "memory");

    // ---- QK^T: S[q0+wid*16+*, kv0+*] ----
    f32x4 sa[4];
    for (int nn = 0; nn < 4; ++nn) {
      sa[nn] = f32x4{0.f, 0.f, 0.f, 0.f};
      const int rowk = nn * 16 + c;
      const int base = rowk * 128;
      const int swz  = (rowk & 7) << 4;
      for (int kc = 0; kc < 2; ++kc) {
        short8 kf = *(const short8*)(Kbyte + base + ((kc * 64 + 16 * g) ^ swz));
        sa[nn] = __builtin_amdgcn_mfma_f32_16x16x32_bf16(qf[kc], kf, sa[nn], 0, 0, 0);
      }
    }

    // ---- causal mask + online softmax (scores already in log2 domain) ----
    const bool diag = (t == ntiles - 1);
    float pp[4][4];
    for (int i = 0; i < 4; ++i) {
      const int qg_ = q0 + wid * 16 + 4 * g + i;
      float s0v = sa[0][i], s1v = sa[1][i], s2v = sa[2][i], s3v = sa[3][i];
      if (diag) {
        if (kv0 +  0 + c > qg_) s0v = -__builtin_inff();
        if (kv0 + 16 + c > qg_) s1v = -__builtin_inff();
        if (kv0 + 32 + c > qg_) s2v = -__builtin_inff();
        if (kv0 + 48 + c > qg_) s3v = -__builtin_inff();
      }
      float mx = fmaxf(fmaxf(s0v, s1v), fmaxf(s2v, s3v));
      mx = fmaxf(mx, __shfl_xor(mx, 1));
      mx = fmaxf(mx, __shfl_xor(mx, 2));
      mx = fmaxf(mx, __shfl_xor(mx, 4));
      mx = fmaxf(mx, __shfl_xor(mx, 8));
      const float nm = fmaxf(mrow[i], mx);
      const float al = exp2f(mrow[i] - nm);
      mrow[i] = nm;
      float p0 = exp2f(s0v - nm), p1 = exp2f(s1v - nm);
      float p2 = exp2f(s2v - nm), p3 = exp2f(s3v - nm);
      pp[0][i] = p0; pp[1][i] = p1; pp[2][i] = p2; pp[3][i] = p3;
      float ls = p0 + p1 + p2 + p3;
      ls += __shfl_xor(ls, 1);
      ls += __shfl_xor(ls, 2);
      ls += __shfl_xor(ls, 4);
      ls += __shfl_xor(ls, 8);
      lrow[i] = lrow[i] * al + ls;
      oa[0][i] *= al; oa[1][i] *= al; oa[2][i] *= al; oa[3][i] *= al;
    }

    // ---- P -> per-wave LDS (bf16), rows padded to 72 ----
    for (int nn = 0; nn < 4; ++nn)
      for (int i = 0; i < 4; ++i)
        *(u16*)(Pbyte + ((4 * g + i) * 72 + nn * 16 + c) * 2) = f2bf(pp[nn][i]);

    // ---- PV: O += P @ V ----
    for (int kc = 0; kc < 2; ++kc) {
      short8 af = *(const short8*)(Pbyte + c * 144 + kc * 64 + 16 * g);
      for (int nd = 0; nd < 4; ++nd) {
        const int d = nd * 16 + c;
        P2 pv;
        pv.a = *(const u64*)(Vbyte + d * 136 + kc * 64 + 16 * g);
        pv.b = *(const u64*)(Vbyte + d * 136 + kc * 64 + 16 * g + 8);
        short8 vf = __builtin_bit_cast(short8, pv);
        oa[nd] = __builtin_amdgcn_mfma_f32_16x16x32_bf16(af, vf, oa[nd], 0, 0, 0);
      }
    }
  }

  // ---- epilogue: normalize and store ----
  for (int i = 0; i < 4; ++i) {
    const float rl = 1.f / lrow[i];
    float* op = Ob + (size_t)(q0 + wid * 16 + 4 * g + i) * D_ + c;
    op[0]  = oa[0][i] * rl;
    op[16] = oa[1][i] * rl;
    op[32] = oa[2][i] * rl;
    op[48] = oa[3][i] * rl;
  }
}

extern "C" void kernel_launch(void* const* d_in, const int* in_sizes, int n_in,
                              void* d_out, int out_size, void* d_ws, size_t ws_size,
                              hipStream_t stream) {
  const float* q = (const float*)d_in[0];
  const float* k = (const float*)d_in[1];
  const float* v = (const float*)d_in[2];
  float* o = (float*)d_out;
  dim3 grid(1024), block(256);
  fattn<<<grid, block, 0, stream>>>(q, k, v, o);
}

// Round 4
// 184.251 us; speedup vs baseline: 1.6344x; 1.0960x over previous
//
#include <hip/hip_runtime.h>
#include <hip/hip_bf16.h>

// Causal flash attention fwd, B=2 H=16 S=2048 D=64, fp32 I/O, bf16 MFMA compute.
// R4 vs R3 (135us dispatch, Mfma 5.3%, VALU 39.8%): pre-convert K/V to bf16 once
// (prologue kernel into d_ws) -> staging loses all f2bf math and half its bytes.
// Kept from R3: balanced qb swizzle, reg-prefetch with lgkm-only barrier B.
// K: LDS [kv][d] bf16 XOR-swizzled (byte ^= (row&7)<<4); V: LDS [d][kv] stride 68;
// P: per-wave [16][72] bf16. MFMA 16x16x32_bf16 layouts per guide §3 (m89-verified).

typedef unsigned int u32;
typedef unsigned short u16;
typedef unsigned long long u64;
typedef __attribute__((ext_vector_type(8))) short short8;
typedef __attribute__((ext_vector_type(4))) float f32x4;

#define DEV static __device__ __forceinline__

constexpr int S_ = 2048, D_ = 64;
constexpr int ELEMS = 2 * 16 * S_ * D_;              // per tensor
constexpr float SCL = 0.125f * 1.44269504089f;       // D^-0.5 * log2(e)

DEV u16 f2bf(float f) {
  u32 u = __builtin_bit_cast(u32, f);
  u += 0x7fffu + ((u >> 16) & 1u);   // RNE; inputs are finite
  return (u16)(u >> 16);
}
DEV u32 pk2(float lo, float hi) { return (u32)f2bf(lo) | ((u32)f2bf(hi) << 16); }
DEV u64 pk4(float4 v) { return (u64)pk2(v.x, v.y) | ((u64)pk2(v.z, v.w) << 32); }

struct Q4 { u32 w[4]; };
struct P2 { u64 a, b; };

// ---------------- prologue: f32 -> bf16 tensor convert ----------------
__global__ __launch_bounds__(256)
void convbf(const float* __restrict__ src, u16* __restrict__ dst, int n4) {
  int i = blockIdx.x * blockDim.x + threadIdx.x;
  const int stride = gridDim.x * blockDim.x;
  for (; i < n4; i += stride) {
    float4 v = ((const float4*)src)[i];
    ((u64*)dst)[i] = pk4(v);
  }
}

// ---------------- main kernel (bf16 K/V from d_ws) ----------------
__global__ __launch_bounds__(256, 4)
void fattn(const float* __restrict__ Qg, const u16* __restrict__ Kbf,
           const u16* __restrict__ Vbf, float* __restrict__ Og)
{
  __shared__ __align__(16) u16 Kl[64 * 64];        // 8 KiB, swizzled
  __shared__ __align__(16) u16 Vt[64 * 68];        // 8.5 KiB, [d][kv] pad-68
  __shared__ __align__(16) u16 Pl[4][16 * 72];     // 9 KiB, per-wave

  const int tid  = threadIdx.x;
  const int wid  = tid >> 6;
  const int lane = tid & 63;
  const int c    = lane & 15;
  const int g    = lane >> 4;

  // balanced block swizzle: CU-resident set {j, j+256, j+512, j+768} gets
  // qb values {b, 31-b, (b+16)&31, (15-b)&31} -> equal total work per CU
  const int n  = blockIdx.x;
  const int j  = n & 255, kq = n >> 8;
  const int b5 = j & 31,  r3 = j >> 5;
  const int bh = kq * 8 + r3;
  int qb;
  switch (kq) {
    case 0:  qb = b5;              break;
    case 1:  qb = 31 - b5;         break;
    case 2:  qb = (b5 + 16) & 31;  break;
    default: qb = (15 - b5) & 31;  break;
  }
  const int q0 = qb * 64;
  const int ntiles = qb + 1;

  const float* Qb = Qg  + (size_t)bh * S_ * D_;
  const u16*   Kb = Kbf + (size_t)bh * S_ * D_;
  const u16*   Vb = Vbf + (size_t)bh * S_ * D_;
  float*       Ob = Og  + (size_t)bh * S_ * D_;

  char* Kbyte = (char*)Kl;
  char* Vbyte = (char*)Vt;
  char* Pbyte = (char*)(Pl[wid]);

  // ---- Q fragments (A operand), scale folded into bf16 conversion ----
  const int qrow = q0 + wid * 16 + c;
  short8 qf[2];
  for (int kc = 0; kc < 2; ++kc) {
    const float* qp = Qb + (size_t)qrow * D_ + kc * 32 + 8 * g;
    float4 x = *(const float4*)qp;
    float4 y = *(const float4*)(qp + 4);
    Q4 q;
    q.w[0] = pk2(x.x * SCL, x.y * SCL);
    q.w[1] = pk2(x.z * SCL, x.w * SCL);
    q.w[2] = pk2(y.x * SCL, y.y * SCL);
    q.w[3] = pk2(y.z * SCL, y.w * SCL);
    qf[kc] = __builtin_bit_cast(short8, q);
  }

  f32x4 oa[4];
  for (int nd = 0; nd < 4; ++nd) oa[nd] = f32x4{0.f, 0.f, 0.f, 0.f};
  float mrow[4], lrow[4];
  for (int i = 0; i < 4; ++i) { mrow[i] = -__builtin_inff(); lrow[i] = 0.f; }

  // ---- prefetch layout ----
  const int m16  = (tid & 7) * 16;     // K: byte col of 16B chunk
  const int rK0  = tid >> 3;           // K: row 0..31 (and +32)
  const int rK1  = rK0 + 32;
  const int cf4  = tid & 15;
  const int d0   = cf4 * 4;            // V: 4 d-cols
  const int kvl0 = 2 * (tid >> 4);     // V: kv row pair (and +32)
  const int kvl1 = kvl0 + 32;
  short8 pkA, pkB;
  u64 pva0, pvb0, pva1, pvb1;

#define ISSUE(T) do {                                                   \
    const u16* Kt_ = Kb + (size_t)(T) * 64 * D_;                        \
    const u16* Vg_ = Vb + (size_t)(T) * 64 * D_;                        \
    pkA  = *(const short8*)((const char*)Kt_ + rK0 * 128 + m16);        \
    pkB  = *(const short8*)((const char*)Kt_ + rK1 * 128 + m16);        \
    pva0 = *(const u64*)(Vg_ + (size_t)(kvl0    ) * D_ + d0);           \
    pvb0 = *(const u64*)(Vg_ + (size_t)(kvl0 + 1) * D_ + d0);           \
    pva1 = *(const u64*)(Vg_ + (size_t)(kvl1    ) * D_ + d0);           \
    pvb1 = *(const u64*)(Vg_ + (size_t)(kvl1 + 1) * D_ + d0);           \
  } while (0)

  ISSUE(0);

  for (int t = 0; t < ntiles; ++t) {
    const int kv0 = t * 64;
    __syncthreads();   // barrier A: all waves done reading previous K/Vt tile
                       // (also drains the prefetch loads we are about to write)

    // ---- write prefetched tile -> LDS (K swizzled; V transposed) ----
    {
      *(short8*)(Kbyte + rK0 * 128 + (m16 ^ ((rK0 & 7) << 4))) = pkA;
      *(short8*)(Kbyte + rK1 * 128 + (m16 ^ ((rK1 & 7) << 4))) = pkB;
      u32 a0 = (u32)pva0, a1 = (u32)(pva0 >> 32);
      u32 b0 = (u32)pvb0, b1 = (u32)(pvb0 >> 32);
      *(u32*)(Vbyte + (d0 + 0) * 136 + kvl0 * 2) = (a0 & 0xffffu) | (b0 << 16);
      *(u32*)(Vbyte + (d0 + 1) * 136 + kvl0 * 2) = (a0 >> 16) | (b0 & 0xffff0000u);
      *(u32*)(Vbyte + (d0 + 2) * 136 + kvl0 * 2) = (a1 & 0xffffu) | (b1 << 16);
      *(u32*)(Vbyte + (d0 + 3) * 136 + kvl0 * 2) = (a1 >> 16) | (b1 & 0xffff0000u);
      a0 = (u32)pva1; a1 = (u32)(pva1 >> 32);
      b0 = (u32)pvb1; b1 = (u32)(pvb1 >> 32);
      *(u32*)(Vbyte + (d0 + 0) * 136 + kvl1 * 2) = (a0 & 0xffffu) | (b0 << 16);
      *(u32*)(Vbyte + (d0 + 1) * 136 + kvl1 * 2) = (a0 >> 16) | (b0 & 0xffff0000u);
      *(u32*)(Vbyte + (d0 + 2) * 136 + kvl1 * 2) = (a1 & 0xffffu) | (b1 << 16);
      *(u32*)(Vbyte + (d0 + 3) * 136 + kvl1 * 2) = (a1 >> 16) | (b1 & 0xffff0000u);
    }

    // ---- issue next tile's global loads (stay in flight across barrier B) ----
    if (t + 1 < ntiles) ISSUE(t + 1);

    // barrier B: drain LDS writes only — NOT vmcnt (keep prefetch in flight)
    asm volatile("s_waitcnt lgkmcnt(0)" ::: "memory");
    __builtin_amdgcn_s_barrier();
    asm volatile("" ::: "memory");

    // ---- QK^T: S[q0+wid*16+*, kv0+*] ----
    f32x4 sa[4];
    for (int nn = 0; nn < 4; ++nn) {
      sa[nn] = f32x4{0.f, 0.f, 0.f, 0.f};
      const int rowk = nn * 16 + c;
      const int base = rowk * 128;
      const int swz  = (rowk & 7) << 4;
      for (int kc = 0; kc < 2; ++kc) {
        short8 kf = *(const short8*)(Kbyte + base + ((kc * 64 + 16 * g) ^ swz));
        sa[nn] = __builtin_amdgcn_mfma_f32_16x16x32_bf16(qf[kc], kf, sa[nn], 0, 0, 0);
      }
    }

    // ---- causal mask + online softmax (scores already in log2 domain) ----
    const bool diag = (t == ntiles - 1);
    float pp[4][4];
    for (int i = 0; i < 4; ++i) {
      const int qg_ = q0 + wid * 16 + 4 * g + i;
      float s0v = sa[0][i], s1v = sa[1][i], s2v = sa[2][i], s3v = sa[3][i];
      if (diag) {
        if (kv0 +  0 + c > qg_) s0v = -__builtin_inff();
        if (kv0 + 16 + c > qg_) s1v = -__builtin_inff();
        if (kv0 + 32 + c > qg_) s2v = -__builtin_inff();
        if (kv0 + 48 + c > qg_) s3v = -__builtin_inff();
      }
      float mx = fmaxf(fmaxf(s0v, s1v), fmaxf(s2v, s3v));
      mx = fmaxf(mx, __shfl_xor(mx, 1));
      mx = fmaxf(mx, __shfl_xor(mx, 2));
      mx = fmaxf(mx, __shfl_xor(mx, 4));
      mx = fmaxf(mx, __shfl_xor(mx, 8));
      const float nm = fmaxf(mrow[i], mx);
      const float al = exp2f(mrow[i] - nm);
      mrow[i] = nm;
      float p0 = exp2f(s0v - nm), p1 = exp2f(s1v - nm);
      float p2 = exp2f(s2v - nm), p3 = exp2f(s3v - nm);
      pp[0][i] = p0; pp[1][i] = p1; pp[2][i] = p2; pp[3][i] = p3;
      float ls = p0 + p1 + p2 + p3;
      ls += __shfl_xor(ls, 1);
      ls += __shfl_xor(ls, 2);
      ls += __shfl_xor(ls, 4);
      ls += __shfl_xor(ls, 8);
      lrow[i] = lrow[i] * al + ls;
      oa[0][i] *= al; oa[1][i] *= al; oa[2][i] *= al; oa[3][i] *= al;
    }

    // ---- P -> per-wave LDS (bf16), rows padded to 72 ----
    for (int nn = 0; nn < 4; ++nn)
      for (int i = 0; i < 4; ++i)
        *(u16*)(Pbyte + ((4 * g + i) * 72 + nn * 16 + c) * 2) = f2bf(pp[nn][i]);

    // ---- PV: O += P @ V ----
    for (int kc = 0; kc < 2; ++kc) {
      short8 af = *(const short8*)(Pbyte + c * 144 + kc * 64 + 16 * g);
      for (int nd = 0; nd < 4; ++nd) {
        const int d = nd * 16 + c;
        P2 pv;
        pv.a = *(const u64*)(Vbyte + d * 136 + kc * 64 + 16 * g);
        pv.b = *(const u64*)(Vbyte + d * 136 + kc * 64 + 16 * g + 8);
        short8 vf = __builtin_bit_cast(short8, pv);
        oa[nd] = __builtin_amdgcn_mfma_f32_16x16x32_bf16(af, vf, oa[nd], 0, 0, 0);
      }
    }
  }

  // ---- epilogue: normalize and store ----
  for (int i = 0; i < 4; ++i) {
    const float rl = 1.f / lrow[i];
    float* op = Ob + (size_t)(q0 + wid * 16 + 4 * g + i) * D_ + c;
    op[0]  = oa[0][i] * rl;
    op[16] = oa[1][i] * rl;
    op[32] = oa[2][i] * rl;
    op[48] = oa[3][i] * rl;
  }
}

// ---------------- fallback (R3 kernel, f32 K/V) — used only if ws too small ----
__global__ __launch_bounds__(256, 4)
void fattn_fb(const float* __restrict__ Qg, const float* __restrict__ Kg,
              const float* __restrict__ Vg, float* __restrict__ Og)
{
  __shared__ __align__(16) u16 Kl[64 * 64];
  __shared__ __align__(16) u16 Vt[64 * 68];
  __shared__ __align__(16) u16 Pl[4][16 * 72];

  const int tid  = threadIdx.x;
  const int wid  = tid >> 6;
  const int lane = tid & 63;
  const int c    = lane & 15;
  const int g    = lane >> 4;

  const int n  = blockIdx.x;
  const int j  = n & 255, kq = n >> 8;
  const int b5 = j & 31,  r3 = j >> 5;
  const int bh = kq * 8 + r3;
  int qb;
  switch (kq) {
    case 0:  qb = b5;              break;
    case 1:  qb = 31 - b5;         break;
    case 2:  qb = (b5 + 16) & 31;  break;
    default: qb = (15 - b5) & 31;  break;
  }
  const int q0 = qb * 64;
  const int ntiles = qb + 1;

  const float* Qb = Qg + (size_t)bh * S_ * D_;
  const float* Kb = Kg + (size_t)bh * S_ * D_;
  const float* Vb = Vg + (size_t)bh * S_ * D_;
  float*       Ob = Og + (size_t)bh * S_ * D_;

  char* Kbyte = (char*)Kl;
  char* Vbyte = (char*)Vt;
  char* Pbyte = (char*)(Pl[wid]);

  const int qrow = q0 + wid * 16 + c;
  short8 qf[2];
  for (int kc = 0; kc < 2; ++kc) {
    const float* qp = Qb + (size_t)qrow * D_ + kc * 32 + 8 * g;
    float4 x = *(const float4*)qp;
    float4 y = *(const float4*)(qp + 4);
    Q4 q;
    q.w[0] = pk2(x.x * SCL, x.y * SCL);
    q.w[1] = pk2(x.z * SCL, x.w * SCL);
    q.w[2] = pk2(y.x * SCL, y.y * SCL);
    q.w[3] = pk2(y.z * SCL, y.w * SCL);
    qf[kc] = __builtin_bit_cast(short8, q);
  }

  f32x4 oa[4];
  for (int nd = 0; nd < 4; ++nd) oa[nd] = f32x4{0.f, 0.f, 0.f, 0.f};
  float mrow[4], lrow[4];
  for (int i = 0; i < 4; ++i) { mrow[i] = -__builtin_inff(); lrow[i] = 0.f; }

  const int cf4  = tid & 15;
  const int krow = tid >> 4;
  const int d0   = cf4 * 4;
  float4 pk0, pk1, pk2v, pk3, pa0, pb0, pa1, pb1;

#define ISSUEF(T) do {                                                    \
    const float* Kt_ = Kb + (size_t)(T) * 64 * D_;                        \
    const float* Vg_ = Vb + (size_t)(T) * 64 * D_;                        \
    pk0 = *(const float4*)(Kt_ + (size_t)(krow     ) * D_ + d0);          \
    pk1 = *(const float4*)(Kt_ + (size_t)(krow + 16) * D_ + d0);          \
    pk2v = *(const float4*)(Kt_ + (size_t)(krow + 32) * D_ + d0);         \
    pk3 = *(const float4*)(Kt_ + (size_t)(krow + 48) * D_ + d0);          \
    const float* s0_ = Vg_ + (size_t)(2 * krow     ) * D_ + d0;           \
    const float* s1_ = Vg_ + (size_t)(2 * krow + 32) * D_ + d0;           \
    pa0 = *(const float4*)s0_;  pb0 = *(const float4*)(s0_ + D_);         \
    pa1 = *(const float4*)s1_;  pb1 = *(const float4*)(s1_ + D_);         \
  } while (0)

  ISSUEF(0);

  for (int t = 0; t < ntiles; ++t) {
    const int kv0 = t * 64;
    __syncthreads();
    {
      const int r0 = krow, r1 = krow + 16, r2 = krow + 32, r3r = krow + 48;
      *(u64*)(Kbyte + r0  * 128 + ((cf4 * 8) ^ ((r0  & 7) << 4))) = pk4(pk0);
      *(u64*)(Kbyte + r1  * 128 + ((cf4 * 8) ^ ((r1  & 7) << 4))) = pk4(pk1);
      *(u64*)(Kbyte + r2  * 128 + ((cf4 * 8) ^ ((r2  & 7) << 4))) = pk4(pk2v);
      *(u64*)(Kbyte + r3r * 128 + ((cf4 * 8) ^ ((r3r & 7) << 4))) = pk4(pk3);
      const int kvl0 = 2 * krow, kvl1 = 2 * krow + 32;
      *(u32*)(Vbyte + (d0 + 0) * 136 + kvl0 * 2) = pk2(pa0.x, pb0.x);
      *(u32*)(Vbyte + (d0 + 1) * 136 + kvl0 * 2) = pk2(pa0.y, pb0.y);
      *(u32*)(Vbyte + (d0 + 2) * 136 + kvl0 * 2) = pk2(pa0.z, pb0.z);
      *(u32*)(Vbyte + (d0 + 3) * 136 + kvl0 * 2) = pk2(pa0.w, pb0.w);
      *(u32*)(Vbyte + (d0 + 0) * 136 + kvl1 * 2) = pk2(pa1.x, pb1.x);
      *(u32*)(Vbyte + (d0 + 1) * 136 + kvl1 * 2) = pk2(pa1.y, pb1.y);
      *(u32*)(Vbyte + (d0 + 2) * 136 + kvl1 * 2) = pk2(pa1.z, pb1.z);
      *(u32*)(Vbyte + (d0 + 3) * 136 + kvl1 * 2) = pk2(pa1.w, pb1.w);
    }
    if (t + 1 < ntiles) ISSUEF(t + 1);
    asm volatile("s_waitcnt lgkmcnt(0)" ::: "memory");
    __builtin_amdgcn_s_barrier();
    asm volatile("" ::: "memory");

    f32x4 sa[4];
    for (int nn = 0; nn < 4; ++nn) {
      sa[nn] = f32x4{0.f, 0.f, 0.f, 0.f};
      const int rowk = nn * 16 + c;
      const int base = rowk * 128;
      const int swz  = (rowk & 7) << 4;
      for (int kc = 0; kc < 2; ++kc) {
        short8 kf = *(const short8*)(Kbyte + base + ((kc * 64 + 16 * g) ^ swz));
        sa[nn] = __builtin_amdgcn_mfma_f32_16x16x32_bf16(qf[kc], kf, sa[nn], 0, 0, 0);
      }
    }

    const bool diag = (t == ntiles - 1);
    float pp[4][4];
    for (int i = 0; i < 4; ++i) {
      const int qg_ = q0 + wid * 16 + 4 * g + i;
      float s0v = sa[0][i], s1v = sa[1][i], s2v = sa[2][i], s3v = sa[3][i];
      if (diag) {
        if (kv0 +  0 + c > qg_) s0v = -__builtin_inff();
        if (kv0 + 16 + c > qg_) s1v = -__builtin_inff();
        if (kv0 + 32 + c > qg_) s2v = -__builtin_inff();
        if (kv0 + 48 + c > qg_) s3v = -__builtin_inff();
      }
      float mx = fmaxf(fmaxf(s0v, s1v), fmaxf(s2v, s3v));
      mx = fmaxf(mx, __shfl_xor(mx, 1));
      mx = fmaxf(mx, __shfl_xor(mx, 2));
      mx = fmaxf(mx, __shfl_xor(mx, 4));
      mx = fmaxf(mx, __shfl_xor(mx, 8));
      const float nm = fmaxf(mrow[i], mx);
      const float al = exp2f(mrow[i] - nm);
      mrow[i] = nm;
      float p0 = exp2f(s0v - nm), p1 = exp2f(s1v - nm);
      float p2 = exp2f(s2v - nm), p3 = exp2f(s3v - nm);
      pp[0][i] = p0; pp[1][i] = p1; pp[2][i] = p2; pp[3][i] = p3;
      float ls = p0 + p1 + p2 + p3;
      ls += __shfl_xor(ls, 1);
      ls += __shfl_xor(ls, 2);
      ls += __shfl_xor(ls, 4);
      ls += __shfl_xor(ls, 8);
      lrow[i] = lrow[i] * al + ls;
      oa[0][i] *= al; oa[1][i] *= al; oa[2][i] *= al; oa[3][i] *= al;
    }

    for (int nn = 0; nn < 4; ++nn)
      for (int i = 0; i < 4; ++i)
        *(u16*)(Pbyte + ((4 * g + i) * 72 + nn * 16 + c) * 2) = f2bf(pp[nn][i]);

    for (int kc = 0; kc < 2; ++kc) {
      short8 af = *(const short8*)(Pbyte + c * 144 + kc * 64 + 16 * g);
      for (int nd = 0; nd < 4; ++nd) {
        const int d = nd * 16 + c;
        P2 pv;
        pv.a = *(const u64*)(Vbyte + d * 136 + kc * 64 + 16 * g);
        pv.b = *(const u64*)(Vbyte + d * 136 + kc * 64 + 16 * g + 8);
        short8 vf = __builtin_bit_cast(short8, pv);
        oa[nd] = __builtin_amdgcn_mfma_f32_16x16x32_bf16(af, vf, oa[nd], 0, 0, 0);
      }
    }
  }

  for (int i = 0; i < 4; ++i) {
    const float rl = 1.f / lrow[i];
    float* op = Ob + (size_t)(q0 + wid * 16 + 4 * g + i) * D_ + c;
    op[0]  = oa[0][i] * rl;
    op[16] = oa[1][i] * rl;
    op[32] = oa[2][i] * rl;
    op[48] = oa[3][i] * rl;
  }
}

extern "C" void kernel_launch(void* const* d_in, const int* in_sizes, int n_in,
                              void* d_out, int out_size, void* d_ws, size_t ws_size,
                              hipStream_t stream) {
  const float* q = (const float*)d_in[0];
  const float* k = (const float*)d_in[1];
  const float* v = (const float*)d_in[2];
  float* o = (float*)d_out;

  const size_t need = (size_t)2 * ELEMS * sizeof(u16);   // Kbf + Vbf
  if (ws_size >= need) {
    u16* kbf = (u16*)d_ws;
    u16* vbf = kbf + ELEMS;
    const int n4 = ELEMS / 4;
    convbf<<<1024, 256, 0, stream>>>(k, kbf, n4);
    convbf<<<1024, 256, 0, stream>>>(v, vbf, n4);
    fattn<<<1024, 256, 0, stream>>>(q, kbf, vbf, o);
  } else {
    fattn_fb<<<1024, 256, 0, stream>>>(q, k, v, o);
  }
}

// Round 6
// 174.920 us; speedup vs baseline: 1.7216x; 1.0533x over previous
//
#include <hip/hip_runtime.h>
#include <hip/hip_bf16.h>

// Causal flash attention fwd, B=2 H=16 S=2048 D=64, fp32 I/O, bf16 MFMA compute.
// R5 vs R4 (105us dispatch, VALU 39%, Occ 25%): uniform-runtime pairing --
// grid 512, each block does strips qb=31-p then qb=p (33 tiles total, identical
// across ALL blocks) -> no concurrency drain / no 1-block-per-CU tail.
// Plus T13 defer-max: skip O/l rescale while tile max <= running max + 8.
// Kept: bf16 K/V pre-convert into d_ws, reg-prefetch with lgkm-only barrier B,
// K LDS XOR-swizzle, V LDS [d][kv] pad-68, per-wave P [16][72].
// MFMA 16x16x32_bf16 layouts per guide §3 (m89-verified).

typedef unsigned int u32;
typedef unsigned short u16;
typedef unsigned long long u64;
typedef __attribute__((ext_vector_type(8))) short short8;
typedef __attribute__((ext_vector_type(4))) float f32x4;

#define DEV static __device__ __forceinline__

constexpr int S_ = 2048, D_ = 64;
constexpr int ELEMS = 2 * 16 * S_ * D_;              // per tensor
constexpr float SCL = 0.125f * 1.44269504089f;       // D^-0.5 * log2(e)

DEV u16 f2bf(float f) {
  u32 u = __builtin_bit_cast(u32, f);
  u += 0x7fffu + ((u >> 16) & 1u);   // RNE; inputs are finite
  return (u16)(u >> 16);
}
DEV u32 pk2(float lo, float hi) { return (u32)f2bf(lo) | ((u32)f2bf(hi) << 16); }
DEV u64 pk4(float4 v) { return (u64)pk2(v.x, v.y) | ((u64)pk2(v.z, v.w) << 32); }

struct Q4 { u32 w[4]; };
struct P2 { u64 a, b; };

// ---------------- prologue: f32 -> bf16 tensor convert ----------------
__global__ __launch_bounds__(256)
void convbf(const float* __restrict__ src, u16* __restrict__ dst, int n4) {
  int i = blockIdx.x * blockDim.x + threadIdx.x;
  const int stride = gridDim.x * blockDim.x;
  for (; i < n4; i += stride) {
    float4 v = ((const float4*)src)[i];
    ((u64*)dst)[i] = pk4(v);
  }
}

// ---------------- main kernel (bf16 K/V from d_ws) ----------------
__global__ __launch_bounds__(256, 2)
void fattn(const float* __restrict__ Qg, const u16* __restrict__ Kbf,
           const u16* __restrict__ Vbf, float* __restrict__ Og)
{
  __shared__ __align__(16) u16 Kl[64 * 64];        // 8 KiB, swizzled
  __shared__ __align__(16) u16 Vt[64 * 68];        // 8.5 KiB, [d][kv] pad-68
  __shared__ __align__(16) u16 Pl[4][16 * 72];     // 9 KiB, per-wave

  const int tid  = threadIdx.x;
  const int wid  = tid >> 6;
  const int lane = tid & 63;
  const int c    = lane & 15;
  const int g    = lane >> 4;

  // grid 512: bh fastest (XCD gets 4 heads -> ~4MB K/V, L2-friendly).
  // Each block: strips {31-p, p} -> 33 tiles, uniform across all blocks.
  const int n  = blockIdx.x;
  const int bh = n & 31;
  const int p  = n >> 5;                  // 0..15
  const int qbs[2] = {31 - p, p};

  const float* Qb = Qg  + (size_t)bh * S_ * D_;
  const u16*   Kb = Kbf + (size_t)bh * S_ * D_;
  const u16*   Vb = Vbf + (size_t)bh * S_ * D_;
  float*       Ob = Og  + (size_t)bh * S_ * D_;

  char* Kbyte = (char*)Kl;
  char* Vbyte = (char*)Vt;
  char* Pbyte = (char*)(Pl[wid]);

  // ---- prefetch layout ----
  const int m16  = (tid & 7) * 16;     // K: byte col of 16B chunk
  const int rK0  = tid >> 3;           // K: row 0..31 (and +32)
  const int rK1  = rK0 + 32;
  const int cf4  = tid & 15;
  const int d0   = cf4 * 4;            // V: 4 d-cols
  const int kvl0 = 2 * (tid >> 4);     // V: kv row pair (and +32)
  const int kvl1 = kvl0 + 32;
  short8 pkA, pkB;
  u64 pva0, pvb0, pva1, pvb1;

#define ISSUE(T) do {                                                   \
    const u16* Kt_ = Kb + (size_t)(T) * 64 * D_;                        \
    const u16* Vg_ = Vb + (size_t)(T) * 64 * D_;                        \
    pkA  = *(const short8*)((const char*)Kt_ + rK0 * 128 + m16);        \
    pkB  = *(const short8*)((const char*)Kt_ + rK1 * 128 + m16);        \
    pva0 = *(const u64*)(Vg_ + (size_t)(kvl0    ) * D_ + d0);           \
    pvb0 = *(const u64*)(Vg_ + (size_t)(kvl0 + 1) * D_ + d0);           \
    pva1 = *(const u64*)(Vg_ + (size_t)(kvl1    ) * D_ + d0);           \
    pvb1 = *(const u64*)(Vg_ + (size_t)(kvl1 + 1) * D_ + d0);           \
  } while (0)

  ISSUE(0);

  for (int sp = 0; sp < 2; ++sp) {
    const int qb = qbs[sp];
    const int q0 = qb * 64;
    const int ntiles = qb + 1;

    // ---- Q fragments (A operand), scale folded into bf16 conversion ----
    const int qrow = q0 + wid * 16 + c;
    short8 qf[2];
    for (int kc = 0; kc < 2; ++kc) {
      const float* qp = Qb + (size_t)qrow * D_ + kc * 32 + 8 * g;
      float4 x = *(const float4*)qp;
      float4 y = *(const float4*)(qp + 4);
      Q4 q;
      q.w[0] = pk2(x.x * SCL, x.y * SCL);
      q.w[1] = pk2(x.z * SCL, x.w * SCL);
      q.w[2] = pk2(y.x * SCL, y.y * SCL);
      q.w[3] = pk2(y.z * SCL, y.w * SCL);
      qf[kc] = __builtin_bit_cast(short8, q);
    }

    f32x4 oa[4];
    for (int nd = 0; nd < 4; ++nd) oa[nd] = f32x4{0.f, 0.f, 0.f, 0.f};
    float mrow[4], lrow[4];
    for (int i = 0; i < 4; ++i) { mrow[i] = -__builtin_inff(); lrow[i] = 0.f; }

    for (int t = 0; t < ntiles; ++t) {
      const int kv0 = t * 64;
      __syncthreads();   // barrier A: all waves done reading previous K/Vt tile

      // ---- write prefetched tile -> LDS (K swizzled; V transposed) ----
      {
        *(short8*)(Kbyte + rK0 * 128 + (m16 ^ ((rK0 & 7) << 4))) = pkA;
        *(short8*)(Kbyte + rK1 * 128 + (m16 ^ ((rK1 & 7) << 4))) = pkB;
        u32 a0 = (u32)pva0, a1 = (u32)(pva0 >> 32);
        u32 b0 = (u32)pvb0, b1 = (u32)(pvb0 >> 32);
        *(u32*)(Vbyte + (d0 + 0) * 136 + kvl0 * 2) = (a0 & 0xffffu) | (b0 << 16);
        *(u32*)(Vbyte + (d0 + 1) * 136 + kvl0 * 2) = (a0 >> 16) | (b0 & 0xffff0000u);
        *(u32*)(Vbyte + (d0 + 2) * 136 + kvl0 * 2) = (a1 & 0xffffu) | (b1 << 16);
        *(u32*)(Vbyte + (d0 + 3) * 136 + kvl0 * 2) = (a1 >> 16) | (b1 & 0xffff0000u);
        a0 = (u32)pva1; a1 = (u32)(pva1 >> 32);
        b0 = (u32)pvb1; b1 = (u32)(pvb1 >> 32);
        *(u32*)(Vbyte + (d0 + 0) * 136 + kvl1 * 2) = (a0 & 0xffffu) | (b0 << 16);
        *(u32*)(Vbyte + (d0 + 1) * 136 + kvl1 * 2) = (a0 >> 16) | (b0 & 0xffff0000u);
        *(u32*)(Vbyte + (d0 + 2) * 136 + kvl1 * 2) = (a1 & 0xffffu) | (b1 << 16);
        *(u32*)(Vbyte + (d0 + 3) * 136 + kvl1 * 2) = (a1 >> 16) | (b1 & 0xffff0000u);
      }

      // ---- issue next tile's loads (strip-b tile 0 across the boundary) ----
      if (t + 1 < ntiles) ISSUE(t + 1);
      else if (sp == 0)   ISSUE(0);

      // barrier B: drain LDS writes only — NOT vmcnt (keep prefetch in flight)
      asm volatile("s_waitcnt lgkmcnt(0)" ::: "memory");
      __builtin_amdgcn_s_barrier();
      asm volatile("" ::: "memory");

      // ---- QK^T: S[q0+wid*16+*, kv0+*] ----
      f32x4 sa[4];
      for (int nn = 0; nn < 4; ++nn) {
        sa[nn] = f32x4{0.f, 0.f, 0.f, 0.f};
        const int rowk = nn * 16 + c;
        const int base = rowk * 128;
        const int swz  = (rowk & 7) << 4;
        for (int kc = 0; kc < 2; ++kc) {
          short8 kf = *(const short8*)(Kbyte + base + ((kc * 64 + 16 * g) ^ swz));
          sa[nn] = __builtin_amdgcn_mfma_f32_16x16x32_bf16(qf[kc], kf, sa[nn], 0, 0, 0);
        }
      }

      // ---- causal mask + online softmax (log2 domain) + defer-max (T13) ----
      const bool diag = (t == ntiles - 1);
      float pp[4][4];
      for (int i = 0; i < 4; ++i) {
        const int qg_ = q0 + wid * 16 + 4 * g + i;
        float s0v = sa[0][i], s1v = sa[1][i], s2v = sa[2][i], s3v = sa[3][i];
        if (diag) {
          if (kv0 +  0 + c > qg_) s0v = -__builtin_inff();
          if (kv0 + 16 + c > qg_) s1v = -__builtin_inff();
          if (kv0 + 32 + c > qg_) s2v = -__builtin_inff();
          if (kv0 + 48 + c > qg_) s3v = -__builtin_inff();
        }
        float mx = fmaxf(fmaxf(s0v, s1v), fmaxf(s2v, s3v));
        mx = fmaxf(mx, __shfl_xor(mx, 1));
        mx = fmaxf(mx, __shfl_xor(mx, 2));
        mx = fmaxf(mx, __shfl_xor(mx, 4));
        mx = fmaxf(mx, __shfl_xor(mx, 8));
        // defer-max: only rescale when some row grew its max by > 8
        // (P then bounded by 2^8; f32 l/O accumulators have headroom)
        if (!__all(mx <= mrow[i] + 8.0f)) {
          const float nm = fmaxf(mrow[i], mx);
          const float al = exp2f(mrow[i] - nm);   // 0 on first tile (-inf)
          mrow[i] = nm;
          lrow[i] *= al;
          oa[0][i] *= al; oa[1][i] *= al; oa[2][i] *= al; oa[3][i] *= al;
        }
        const float m_ = mrow[i];
        float p0 = exp2f(s0v - m_), p1 = exp2f(s1v - m_);
        float p2 = exp2f(s2v - m_), p3 = exp2f(s3v - m_);
        pp[0][i] = p0; pp[1][i] = p1; pp[2][i] = p2; pp[3][i] = p3;
        float ls = p0 + p1 + p2 + p3;
        ls += __shfl_xor(ls, 1);
        ls += __shfl_xor(ls, 2);
        ls += __shfl_xor(ls, 4);
        ls += __shfl_xor(ls, 8);
        lrow[i] += ls;
      }

      // ---- P -> per-wave LDS (bf16), rows padded to 72 ----
      for (int nn = 0; nn < 4; ++nn)
        for (int i = 0; i < 4; ++i)
          *(u16*)(Pbyte + ((4 * g + i) * 72 + nn * 16 + c) * 2) = f2bf(pp[nn][i]);

      // ---- PV: O += P @ V ----
      for (int kc = 0; kc < 2; ++kc) {
        short8 af = *(const short8*)(Pbyte + c * 144 + kc * 64 + 16 * g);
        for (int nd = 0; nd < 4; ++nd) {
          const int d = nd * 16 + c;
          P2 pv;
          pv.a = *(const u64*)(Vbyte + d * 136 + kc * 64 + 16 * g);
          pv.b = *(const u64*)(Vbyte + d * 136 + kc * 64 + 16 * g + 8);
          short8 vf = __builtin_bit_cast(short8, pv);
          oa[nd] = __builtin_amdgcn_mfma_f32_16x16x32_bf16(af, vf, oa[nd], 0, 0, 0);
        }
      }
    }

    // ---- epilogue: normalize and store this strip ----
    for (int i = 0; i < 4; ++i) {
      const float rl = 1.f / lrow[i];
      float* op = Ob + (size_t)(q0 + wid * 16 + 4 * g + i) * D_ + c;
      op[0]  = oa[0][i] * rl;
      op[16] = oa[1][i] * rl;
      op[32] = oa[2][i] * rl;
      op[48] = oa[3][i] * rl;
    }
  }
}

// ---------------- fallback (f32 K/V, unpaired R4 form) — only if ws too small ----
__global__ __launch_bounds__(256, 4)
void fattn_fb(const float* __restrict__ Qg, const float* __restrict__ Kg,
              const float* __restrict__ Vg, float* __restrict__ Og)
{
  __shared__ __align__(16) u16 Kl[64 * 64];
  __shared__ __align__(16) u16 Vt[64 * 68];
  __shared__ __align__(16) u16 Pl[4][16 * 72];

  const int tid  = threadIdx.x;
  const int wid  = tid >> 6;
  const int lane = tid & 63;
  const int c    = lane & 15;
  const int g    = lane >> 4;

  const int n  = blockIdx.x;
  const int j  = n & 255, kq = n >> 8;
  const int b5 = j & 31,  r3 = j >> 5;
  const int bh = kq * 8 + r3;
  int qb;
  switch (kq) {
    case 0:  qb = b5;              break;
    case 1:  qb = 31 - b5;         break;
    case 2:  qb = (b5 + 16) & 31;  break;
    default: qb = (15 - b5) & 31;  break;
  }
  const int q0 = qb * 64;
  const int ntiles = qb + 1;

  const float* Qb = Qg + (size_t)bh * S_ * D_;
  const float* Kb = Kg + (size_t)bh * S_ * D_;
  const float* Vb = Vg + (size_t)bh * S_ * D_;
  float*       Ob = Og + (size_t)bh * S_ * D_;

  char* Kbyte = (char*)Kl;
  char* Vbyte = (char*)Vt;
  char* Pbyte = (char*)(Pl[wid]);

  const int qrow = q0 + wid * 16 + c;
  short8 qf[2];
  for (int kc = 0; kc < 2; ++kc) {
    const float* qp = Qb + (size_t)qrow * D_ + kc * 32 + 8 * g;
    float4 x = *(const float4*)qp;
    float4 y = *(const float4*)(qp + 4);
    Q4 q;
    q.w[0] = pk2(x.x * SCL, x.y * SCL);
    q.w[1] = pk2(x.z * SCL, x.w * SCL);
    q.w[2] = pk2(y.x * SCL, y.y * SCL);
    q.w[3] = pk2(y.z * SCL, y.w * SCL);
    qf[kc] = __builtin_bit_cast(short8, q);
  }

  f32x4 oa[4];
  for (int nd = 0; nd < 4; ++nd) oa[nd] = f32x4{0.f, 0.f, 0.f, 0.f};
  float mrow[4], lrow[4];
  for (int i = 0; i < 4; ++i) { mrow[i] = -__builtin_inff(); lrow[i] = 0.f; }

  const int cf4  = tid & 15;
  const int krow = tid >> 4;
  const int d0   = cf4 * 4;
  float4 pk0, pk1, pk2v, pk3, pa0, pb0, pa1, pb1;

#define ISSUEF(T) do {                                                    \
    const float* Kt_ = Kb + (size_t)(T) * 64 * D_;                        \
    const float* Vg_ = Vb + (size_t)(T) * 64 * D_;                        \
    pk0 = *(const float4*)(Kt_ + (size_t)(krow     ) * D_ + d0);          \
    pk1 = *(const float4*)(Kt_ + (size_t)(krow + 16) * D_ + d0);          \
    pk2v = *(const float4*)(Kt_ + (size_t)(krow + 32) * D_ + d0);         \
    pk3 = *(const float4*)(Kt_ + (size_t)(krow + 48) * D_ + d0);          \
    const float* s0_ = Vg_ + (size_t)(2 * krow     ) * D_ + d0;           \
    const float* s1_ = Vg_ + (size_t)(2 * krow + 32) * D_ + d0;           \
    pa0 = *(const float4*)s0_;  pb0 = *(const float4*)(s0_ + D_);         \
    pa1 = *(const float4*)s1_;  pb1 = *(const float4*)(s1_ + D_);         \
  } while (0)

  ISSUEF(0);

  for (int t = 0; t < ntiles; ++t) {
    const int kv0 = t * 64;
    __syncthreads();
    {
      const int r0 = krow, r1 = krow + 16, r2 = krow + 32, r3r = krow + 48;
      *(u64*)(Kbyte + r0  * 128 + ((cf4 * 8) ^ ((r0  & 7) << 4))) = pk4(pk0);
      *(u64*)(Kbyte + r1  * 128 + ((cf4 * 8) ^ ((r1  & 7) << 4))) = pk4(pk1);
      *(u64*)(Kbyte + r2  * 128 + ((cf4 * 8) ^ ((r2  & 7) << 4))) = pk4(pk2v);
      *(u64*)(Kbyte + r3r * 128 + ((cf4 * 8) ^ ((r3r & 7) << 4))) = pk4(pk3);
      const int kvl0 = 2 * krow, kvl1 = 2 * krow + 32;
      *(u32*)(Vbyte + (d0 + 0) * 136 + kvl0 * 2) = pk2(pa0.x, pb0.x);
      *(u32*)(Vbyte + (d0 + 1) * 136 + kvl0 * 2) = pk2(pa0.y, pb0.y);
      *(u32*)(Vbyte + (d0 + 2) * 136 + kvl0 * 2) = pk2(pa0.z, pb0.z);
      *(u32*)(Vbyte + (d0 + 3) * 136 + kvl0 * 2) = pk2(pa0.w, pb0.w);
      *(u32*)(Vbyte + (d0 + 0) * 136 + kvl1 * 2) = pk2(pa1.x, pb1.x);
      *(u32*)(Vbyte + (d0 + 1) * 136 + kvl1 * 2) = pk2(pa1.y, pb1.y);
      *(u32*)(Vbyte + (d0 + 2) * 136 + kvl1 * 2) = pk2(pa1.z, pb1.z);
      *(u32*)(Vbyte + (d0 + 3) * 136 + kvl1 * 2) = pk2(pa1.w, pb1.w);
    }
    if (t + 1 < ntiles) ISSUEF(t + 1);
    asm volatile("s_waitcnt lgkmcnt(0)" ::: "memory");
    __builtin_amdgcn_s_barrier();
    asm volatile("" ::: "memory");

    f32x4 sa[4];
    for (int nn = 0; nn < 4; ++nn) {
      sa[nn] = f32x4{0.f, 0.f, 0.f, 0.f};
      const int rowk = nn * 16 + c;
      const int base = rowk * 128;
      const int swz  = (rowk & 7) << 4;
      for (int kc = 0; kc < 2; ++kc) {
        short8 kf = *(const short8*)(Kbyte + base + ((kc * 64 + 16 * g) ^ swz));
        sa[nn] = __builtin_amdgcn_mfma_f32_16x16x32_bf16(qf[kc], kf, sa[nn], 0, 0, 0);
      }
    }

    const bool diag = (t == ntiles - 1);
    float pp[4][4];
    for (int i = 0; i < 4; ++i) {
      const int qg_ = q0 + wid * 16 + 4 * g + i;
      float s0v = sa[0][i], s1v = sa[1][i], s2v = sa[2][i], s3v = sa[3][i];
      if (diag) {
        if (kv0 +  0 + c > qg_) s0v = -__builtin_inff();
        if (kv0 + 16 + c > qg_) s1v = -__builtin_inff();
        if (kv0 + 32 + c > qg_) s2v = -__builtin_inff();
        if (kv0 + 48 + c > qg_) s3v = -__builtin_inff();
      }
      float mx = fmaxf(fmaxf(s0v, s1v), fmaxf(s2v, s3v));
      mx = fmaxf(mx, __shfl_xor(mx, 1));
      mx = fmaxf(mx, __shfl_xor(mx, 2));
      mx = fmaxf(mx, __shfl_xor(mx, 4));
      mx = fmaxf(mx, __shfl_xor(mx, 8));
      const float nm = fmaxf(mrow[i], mx);
      const float al = exp2f(mrow[i] - nm);
      mrow[i] = nm;
      float p0 = exp2f(s0v - nm), p1 = exp2f(s1v - nm);
      float p2 = exp2f(s2v - nm), p3 = exp2f(s3v - nm);
      pp[0][i] = p0; pp[1][i] = p1; pp[2][i] = p2; pp[3][i] = p3;
      float ls = p0 + p1 + p2 + p3;
      ls += __shfl_xor(ls, 1);
      ls += __shfl_xor(ls, 2);
      ls += __shfl_xor(ls, 4);
      ls += __shfl_xor(ls, 8);
      lrow[i] = lrow[i] * al + ls;
      oa[0][i] *= al; oa[1][i] *= al; oa[2][i] *= al; oa[3][i] *= al;
    }

    for (int nn = 0; nn < 4; ++nn)
      for (int i = 0; i < 4; ++i)
        *(u16*)(Pbyte + ((4 * g + i) * 72 + nn * 16 + c) * 2) = f2bf(pp[nn][i]);

    for (int kc = 0; kc < 2; ++kc) {
      short8 af = *(const short8*)(Pbyte + c * 144 + kc * 64 + 16 * g);
      for (int nd = 0; nd < 4; ++nd) {
        const int d = nd * 16 + c;
        P2 pv;
        pv.a = *(const u64*)(Vbyte + d * 136 + kc * 64 + 16 * g);
        pv.b = *(const u64*)(Vbyte + d * 136 + kc * 64 + 16 * g + 8);
        short8 vf = __builtin_bit_cast(short8, pv);
        oa[nd] = __builtin_amdgcn_mfma_f32_16x16x32_bf16(af, vf, oa[nd], 0, 0, 0);
      }
    }
  }

  for (int i = 0; i < 4; ++i) {
    const float rl = 1.f / lrow[i];
    float* op = Ob + (size_t)(q0 + wid * 16 + 4 * g + i) * D_ + c;
    op[0]  = oa[0][i] * rl;
    op[16] = oa[1][i] * rl;
    op[32] = oa[2][i] * rl;
    op[48] = oa[3][i] * rl;
  }
}

extern "C" void kernel_launch(void* const* d_in, const int* in_sizes, int n_in,
                              void* d_out, int out_size, void* d_ws, size_t ws_size,
                              hipStream_t stream) {
  const float* q = (const float*)d_in[0];
  const float* k = (const float*)d_in[1];
  const float* v = (const float*)d_in[2];
  float* o = (float*)d_out;

  const size_t need = (size_t)2 * ELEMS * sizeof(u16);   // Kbf + Vbf
  if (ws_size >= need) {
    u16* kbf = (u16*)d_ws;
    u16* vbf = kbf + ELEMS;
    const int n4 = ELEMS / 4;
    convbf<<<1024, 256, 0, stream>>>(k, kbf, n4);
    convbf<<<1024, 256, 0, stream>>>(v, vbf, n4);
    fattn<<<512, 256, 0, stream>>>(q, kbf, vbf, o);
  } else {
    fattn_fb<<<1024, 256, 0, stream>>>(q, k, v, o);
  }
}